// Round 11
// baseline (314.854 us; speedup 1.0000x reference)
//
#include <hip/hip_runtime.h>

#define N_NODES   100000
#define N_EDGES   3200000
#define D_IN      128
#define H1F       32
#define H2F       64
#define N_CLASSES 10
#define N_GRAPHS  64

#define NBUCK 391      // ceil(100000 / 256) buckets of 256 nodes
#define CAP   10240    // col slab capacity (u32); mean fill 8192, sigma~90
#define RCAP  10240    // row slab capacity (bytes)
#define EPB   3072
#define NPB   ((N_EDGES + EPB - 1) / EPB)   // 1042

// bf16 helpers (RNE pack)
__device__ __forceinline__ unsigned f2bf(float f) {
    unsigned u = __float_as_uint(f);
    return (u + 0x7fffu + ((u >> 16) & 1u)) >> 16;
}
__device__ __forceinline__ float bf2f(unsigned h) {
    return __uint_as_float(h << 16);
}

// ---------------- LDS-staged partition into slabs (coalesced write-out) ----------------
// cursors cpos/rpos are SLAB-RELATIVE (zero-initialized by hipMemsetAsync)
__global__ __launch_bounds__(256) void k_part(const int* __restrict__ row,
        const int* __restrict__ col, int* cpos, int* rpos,
        unsigned* __restrict__ partc, unsigned char* __restrict__ partr) {
    __shared__ int sc[512], sr[512];            // histogram -> inclusive scan
    __shared__ int posc[NBUCK], posr[NBUCK];    // scatter cursors (local)
    __shared__ int basec[NBUCK], baser[NBUCK];  // global slab bases
    __shared__ unsigned stagc[EPB];             // 12.3 KB
    __shared__ unsigned char stagr[EPB];        // 3 KB
    __shared__ unsigned short stagcb[EPB];      // 6.1 KB  bucket id per staged col elem
    __shared__ unsigned short stagrb[EPB];      // 6.1 KB  bucket id per staged row elem
    int t = threadIdx.x;
    sc[t] = 0; sc[t + 256] = 0; sr[t] = 0; sr[t + 256] = 0;
    __syncthreads();
    int s = blockIdx.x * EPB;
    int e = min(s + EPB, N_EDGES);
    // phase A: local histograms
    for (int i = s + t; i < e; i += 256) {
        atomicAdd(&sc[col[i] >> 8], 1);
        atomicAdd(&sr[row[i] >> 8], 1);
    }
    __syncthreads();
    // phase B: inclusive scan over 512 (2 slots/thread)
    for (int o = 1; o < 512; o <<= 1) {
        int a0 = (t >= o) ? sc[t - o] : 0;
        int a1 = sc[t + 256 - o];
        int b0 = (t >= o) ? sr[t - o] : 0;
        int b1 = sr[t + 256 - o];
        __syncthreads();
        sc[t] += a0; sc[t + 256] += a1;
        sr[t] += b0; sr[t + 256] += b1;
        __syncthreads();
    }
    // phase C: per-bucket local starts + global slab reservations
    for (int b = t; b < NBUCK; b += 256) {
        int cc = sc[b] - (b ? sc[b - 1] : 0);
        int rc = sr[b] - (b ? sr[b - 1] : 0);
        posc[b] = sc[b] - cc;
        posr[b] = sr[b] - rc;
        basec[b] = cc ? (b * CAP + atomicAdd(&cpos[b], cc)) : 0;
        baser[b] = rc ? (b * RCAP + atomicAdd(&rpos[b], rc)) : 0;
    }
    __syncthreads();
    // phase D: scatter into LDS staging (edge re-read is L2-hot); record bucket id
    for (int i = s + t; i < e; i += 256) {
        int c = col[i], r = row[i];
        int b = c >> 8;
        int p = atomicAdd(&posc[b], 1);
        stagc[p] = ((unsigned)(c & 255) << 17) | (unsigned)r;  // row < 2^17
        stagcb[p] = (unsigned short)b;
        int b2 = r >> 8;
        int p2 = atomicAdd(&posr[b2], 1);
        stagr[p2] = (unsigned char)(r & 255);
        stagrb[p2] = (unsigned short)b2;
    }
    __syncthreads();
    // phase E: sorted write-out; bucket id via direct lookup (no search)
    int nloc = e - s;
    for (int i = t; i < nloc; i += 256) {
        int b = stagcb[i];
        int start = b ? sc[b - 1] : 0;
        partc[basec[b] + (i - start)] = stagc[i];
    }
    for (int i = t; i < nloc; i += 256) {
        int b = stagrb[i];
        int start = b ? sr[b - 1] : 0;
        partr[baser[b] + (i - start)] = stagr[i];
    }
}

// ---------------- per-bucket work: col -> CSR (srcoff + srcw); row -> dis ----------------
__global__ __launch_bounds__(256) void k_buckets(const unsigned* __restrict__ partc,
        const unsigned char* __restrict__ partr, const int* __restrict__ cpos,
        const int* __restrict__ rpos, int2* __restrict__ srcoff,
        int* __restrict__ srcw, float* __restrict__ dis) {
    int t = threadIdx.x;
    if (blockIdx.x < NBUCK) {
        // ---- col bucket: per-node counts, scan, sorted fill ----
        __shared__ int cnt[256], sc[256], run[256];
        int b = blockIdx.x;
        cnt[t] = 0; run[t] = 0;
        __syncthreads();
        int s = b * CAP, e = s + cpos[b];
        for (int i = s + t; i < e; i += 256)
            atomicAdd(&cnt[partc[i] >> 17], 1);
        __syncthreads();
        int v = cnt[t]; sc[t] = v; __syncthreads();
        for (int o = 1; o < 256; o <<= 1) {
            int a = (t >= o) ? sc[t - o] : 0;
            __syncthreads();
            sc[t] += a;
            __syncthreads();
        }
        int ex = sc[t] - v;
        __syncthreads();
        sc[t] = ex;
        __syncthreads();
        int n = (b << 8) + t;
        if (n < N_NODES) srcoff[n] = make_int2(s + ex, s + ex + v);
        for (int i = s + t; i < e; i += 256) {
            unsigned p = partc[i];
            int c = p >> 17;
            int k = atomicAdd(&run[c], 1);
            srcw[s + sc[c] + k] = (int)(p & 0x1FFFFu);
        }
    } else {
        // ---- row bucket: out-degree histogram -> dis ----
        __shared__ int cnt[256];
        int b = blockIdx.x - NBUCK;
        cnt[t] = 0;
        __syncthreads();
        int s = b * RCAP, e = s + rpos[b];
        for (int i = s + t; i < e; i += 256) atomicAdd(&cnt[partr[i]], 1);
        __syncthreads();
        int n = (b << 8) + t;
        if (n < N_NODES) dis[n] = rsqrtf((float)(1 + cnt[t]));  // +1 self-loop
    }
}

// ---------------- lin1: hs1b = bf16( dis[n] * (x W1^T + b1) ) ----------------
__global__ __launch_bounds__(256) void k_lin1(const float* __restrict__ x,
        const float* __restrict__ W1, const float* __restrict__ b1,
        const float* __restrict__ dis, unsigned* __restrict__ hs1b) {
    __shared__ float w1t[D_IN][H1F + 1];
    __shared__ float xs[8][D_IN];
    int tid = threadIdx.x;
    for (int idx = tid; idx < H1F * D_IN; idx += 256) {
        int f = idx >> 7, k = idx & 127;
        w1t[k][f] = W1[idx];
    }
    int nbase = blockIdx.x * 8;
    for (int idx = tid; idx < 8 * D_IN; idx += 256) {
        int nn = idx >> 7, k = idx & 127;
        int n = nbase + nn;
        xs[nn][k] = (n < N_NODES) ? x[(long long)n * D_IN + k] : 0.0f;
    }
    __syncthreads();
    int f = tid & 31, sub = tid >> 5;
    int n = nbase + sub;
    float acc = 0.f;
    #pragma unroll
    for (int k = 0; k < D_IN; ++k) acc += xs[sub][k] * w1t[k][f];
    float val = (n < N_NODES) ? dis[n] * (acc + b1[f]) : 0.f;
    float other = __shfl_xor(val, 1);
    if ((f & 1) == 0 && n < N_NODES)
        hs1b[n * 16 + (f >> 1)] = f2bf(val) | (f2bf(other) << 16);
}

// ---------------- gather1: hs2b = bf16( dis_c * relu( dis_c*(hs1_c + sum hs1_src) ) ) ----
__global__ __launch_bounds__(256) void k_gather1(const int* __restrict__ srcw,
        const int2* __restrict__ srcoff, const float* __restrict__ dis,
        const unsigned* __restrict__ hs, unsigned* __restrict__ out) {
    int lane = threadIdx.x & 63;
    int c = (blockIdx.x * 256 + threadIdx.x) >> 6;
    if (c >= N_NODES) return;
    int e8 = lane >> 3, l8 = lane & 7;
    int2 so = srcoff[c];
    int s = so.x, e = so.y;
    float a0 = 0.f, a1 = 0.f, a2 = 0.f, a3 = 0.f;
    if (e8 == 0) {
        uint2 u = ((const uint2*)(hs + c * 16))[l8];
        a0 = bf2f(u.x & 0xffffu); a1 = bf2f(u.x >> 16);
        a2 = bf2f(u.y & 0xffffu); a3 = bf2f(u.y >> 16);
    }
    int j = s + e8;
    for (; j + 8 < e; j += 16) {
        int s0 = srcw[j], s1 = srcw[j + 8];
        uint2 u0 = ((const uint2*)(hs + s0 * 16))[l8];
        uint2 u1 = ((const uint2*)(hs + s1 * 16))[l8];
        a0 += bf2f(u0.x & 0xffffu); a1 += bf2f(u0.x >> 16);
        a2 += bf2f(u0.y & 0xffffu); a3 += bf2f(u0.y >> 16);
        a0 += bf2f(u1.x & 0xffffu); a1 += bf2f(u1.x >> 16);
        a2 += bf2f(u1.y & 0xffffu); a3 += bf2f(u1.y >> 16);
    }
    if (j < e) {
        uint2 u0 = ((const uint2*)(hs + srcw[j] * 16))[l8];
        a0 += bf2f(u0.x & 0xffffu); a1 += bf2f(u0.x >> 16);
        a2 += bf2f(u0.y & 0xffffu); a3 += bf2f(u0.y >> 16);
    }
    a0 += __shfl_xor(a0, 8);  a1 += __shfl_xor(a1, 8);
    a2 += __shfl_xor(a2, 8);  a3 += __shfl_xor(a3, 8);
    a0 += __shfl_xor(a0, 16); a1 += __shfl_xor(a1, 16);
    a2 += __shfl_xor(a2, 16); a3 += __shfl_xor(a3, 16);
    a0 += __shfl_xor(a0, 32); a1 += __shfl_xor(a1, 32);
    a2 += __shfl_xor(a2, 32); a3 += __shfl_xor(a3, 32);
    if (e8 == 0) {
        float dc = dis[c];
        uint2 w;
        w.x = f2bf(dc * fmaxf(dc * a0, 0.f)) | (f2bf(dc * fmaxf(dc * a1, 0.f)) << 16);
        w.y = f2bf(dc * fmaxf(dc * a2, 0.f)) | (f2bf(dc * fmaxf(dc * a3, 0.f)) << 16);
        ((uint2*)(out + c * 16))[l8] = w;
    }
}

// ---------------- gather2: G = dis_c*(hs2_c + sum hs2_src) [32 fp32], Sd = dis_c*(dis_c+sum dis_src)
__global__ __launch_bounds__(256) void k_gather2(const int* __restrict__ srcw,
        const int2* __restrict__ srcoff, const float* __restrict__ dis,
        const unsigned* __restrict__ hs, float* __restrict__ G,
        float* __restrict__ Sd) {
    int lane = threadIdx.x & 63;
    int c = (blockIdx.x * 256 + threadIdx.x) >> 6;
    if (c >= N_NODES) return;
    int e8 = lane >> 3, l8 = lane & 7;
    int2 so = srcoff[c];
    int s = so.x, e = so.y;
    float a0 = 0.f, a1 = 0.f, a2 = 0.f, a3 = 0.f, ad = 0.f;
    if (e8 == 0) {
        uint2 u = ((const uint2*)(hs + c * 16))[l8];
        a0 = bf2f(u.x & 0xffffu); a1 = bf2f(u.x >> 16);
        a2 = bf2f(u.y & 0xffffu); a3 = bf2f(u.y >> 16);
    }
    int j = s + e8;
    for (; j + 8 < e; j += 16) {
        int s0 = srcw[j], s1 = srcw[j + 8];
        uint2 u0 = ((const uint2*)(hs + s0 * 16))[l8];
        uint2 u1 = ((const uint2*)(hs + s1 * 16))[l8];
        if (l8 == 0) ad += dis[s0] + dis[s1];
        a0 += bf2f(u0.x & 0xffffu); a1 += bf2f(u0.x >> 16);
        a2 += bf2f(u0.y & 0xffffu); a3 += bf2f(u0.y >> 16);
        a0 += bf2f(u1.x & 0xffffu); a1 += bf2f(u1.x >> 16);
        a2 += bf2f(u1.y & 0xffffu); a3 += bf2f(u1.y >> 16);
    }
    if (j < e) {
        int s0 = srcw[j];
        uint2 u0 = ((const uint2*)(hs + s0 * 16))[l8];
        if (l8 == 0) ad += dis[s0];
        a0 += bf2f(u0.x & 0xffffu); a1 += bf2f(u0.x >> 16);
        a2 += bf2f(u0.y & 0xffffu); a3 += bf2f(u0.y >> 16);
    }
    a0 += __shfl_xor(a0, 8);  a1 += __shfl_xor(a1, 8);
    a2 += __shfl_xor(a2, 8);  a3 += __shfl_xor(a3, 8);
    ad += __shfl_xor(ad, 8);
    a0 += __shfl_xor(a0, 16); a1 += __shfl_xor(a1, 16);
    a2 += __shfl_xor(a2, 16); a3 += __shfl_xor(a3, 16);
    ad += __shfl_xor(ad, 16);
    a0 += __shfl_xor(a0, 32); a1 += __shfl_xor(a1, 32);
    a2 += __shfl_xor(a2, 32); a3 += __shfl_xor(a3, 32);
    ad += __shfl_xor(ad, 32);
    if (e8 == 0) {
        float dc = dis[c];
        float4 w; w.x = dc * a0; w.y = dc * a1; w.z = dc * a2; w.w = dc * a3;
        *(float4*)(&G[c * 32 + l8 * 4]) = w;
        if (l8 == 0) Sd[c] = dc * (dc + ad);
    }
}

// ---------------- fused lin2 + relu + mean-pool accumulate ----------------
__global__ __launch_bounds__(256) void k_lin2pool(const float* __restrict__ G,
        const float* __restrict__ Sd, const float* __restrict__ W2,
        const float* __restrict__ b2, const int* __restrict__ batch,
        float* __restrict__ sums) {
    __shared__ float w2t[H1F][H2F + 1];
    int tid = threadIdx.x;
    for (int idx = tid; idx < H2F * H1F; idx += 256) {
        int fo = idx >> 5, k = idx & 31;
        w2t[k][fo] = W2[idx];
    }
    __syncthreads();
    int f = tid & 63, sub = tid >> 6;
    float bfv = b2[f];
    int n0 = blockIdx.x * 256;
    float acc = 0.f; int gcur = -1;
    for (int i = sub; i < 256; i += 4) {
        int n = n0 + i;
        if (n >= N_NODES) break;
        const float4* Gr = (const float4*)(&G[n * 32]);
        float d = Sd[n] * bfv;
        #pragma unroll
        for (int q = 0; q < 8; ++q) {
            float4 v = Gr[q];
            d += v.x * w2t[4 * q][f] + v.y * w2t[4 * q + 1][f]
               + v.z * w2t[4 * q + 2][f] + v.w * w2t[4 * q + 3][f];
        }
        d = fmaxf(d, 0.f);
        int gg = batch[n];
        if (gg != gcur) {
            if (gcur >= 0) atomicAdd(&sums[gcur * H2F + f], acc);
            acc = 0.f; gcur = gg;
        }
        acc += d;
    }
    if (gcur >= 0) atomicAdd(&sums[gcur * H2F + f], acc);
}

// ---------------- final: counts (binary search) + mean + linear + softmax ----------------
__global__ __launch_bounds__(640) void k_final(const float* __restrict__ sums,
        const int* __restrict__ batch, const float* __restrict__ Wf,
        const float* __restrict__ bf, float* __restrict__ out) {
    __shared__ float l[N_GRAPHS * N_CLASSES];
    __shared__ float cnts[N_GRAPHS];
    int tid = threadIdx.x;
    if (tid < N_GRAPHS) {
        int g = tid;
        int lo = 0, hi = N_NODES;
        while (lo < hi) { int mid = (lo + hi) >> 1; if (batch[mid] < g) lo = mid + 1; else hi = mid; }
        int start = lo;
        hi = N_NODES;
        while (lo < hi) { int mid = (lo + hi) >> 1; if (batch[mid] < g + 1) lo = mid + 1; else hi = mid; }
        cnts[g] = (float)(lo - start);
    }
    __syncthreads();
    if (tid < N_GRAPHS * N_CLASSES) {
        int g = tid / N_CLASSES, c = tid % N_CLASSES;
        float cnt = fmaxf(cnts[g], 1.0f);
        float acc = bf[c];
        for (int f = 0; f < H2F; ++f)
            acc += (sums[g * H2F + f] / cnt) * Wf[c * H2F + f];
        l[tid] = acc;
    }
    __syncthreads();
    if (tid < N_GRAPHS) {
        float m = -1e30f;
        for (int c = 0; c < N_CLASSES; ++c) m = fmaxf(m, l[tid * N_CLASSES + c]);
        float s = 0.f;
        float ex[N_CLASSES];
        for (int c = 0; c < N_CLASSES; ++c) { ex[c] = expf(l[tid * N_CLASSES + c] - m); s += ex[c]; }
        for (int c = 0; c < N_CLASSES; ++c) out[tid * N_CLASSES + c] = ex[c] / s;
    }
}

extern "C" void kernel_launch(void* const* d_in, const int* in_sizes, int n_in,
                              void* d_out, int out_size, void* d_ws, size_t ws_size,
                              hipStream_t stream) {
    const float* x     = (const float*)d_in[0];
    const int*   ei    = (const int*)d_in[1];
    const int*   batch = (const int*)d_in[2];
    const float* W1    = (const float*)d_in[3];
    const float* b1    = (const float*)d_in[4];
    const float* W2    = (const float*)d_in[5];
    const float* b2    = (const float*)d_in[6];
    const float* Wf    = (const float*)d_in[7];
    const float* bf    = (const float*)d_in[8];
    float* out = (float*)d_out;

    const int* row = ei;            // edge_index[0,:] (source)
    const int* col = ei + N_EDGES;  // edge_index[1,:] (dest)

    // workspace layout (int units)
    int* W = (int*)d_ws;
    int*           cpos   = W + 0;          // 400 (slab-relative, zeroed)
    int*           rpos   = W + 400;        // 400 (slab-relative, zeroed)
    float*         sums   = (float*)(W + 800);             // 4096 (zeroed)
    int2*          srcoff = (int2*)(W + 4904);             // 100000 int2 -> 204904
    int*           srcw   = W + 204904;     // slab 391*10240 = 4003840 -> 4208744
    unsigned*      partc  = (unsigned*)(W + 4208744);      // slab 4003840 -> 8212584
    float*         G      = (float*)(W + 4208744);         // alias partc (dead after k_buckets)
    unsigned char* partr  = (unsigned char*)(W + 8212584); // slab 391*10240 B -> +1000960 = 9213544
    float*         dis    = (float*)(W + 9213544);         // 100000
    float*         Sd     = (float*)(W + 9313544);         // 100000
    unsigned*      hs1b   = (unsigned*)(W + 9413544);      // 1.6M -> 11013544
    unsigned*      hs2b   = (unsigned*)(W + 11013544);     // 1.6M -> 12613544
    // total ~50.5 MB

    // zero cursors + sums in one async memset (replaces k_init)
    hipMemsetAsync(W, 0, (800 + N_GRAPHS * H2F) * sizeof(int), stream);

    // ---- CSR build: slab partition + per-bucket sort ----
    k_part<<<NPB, 256, 0, stream>>>(row, col, cpos, rpos, partc, partr);
    k_buckets<<<2 * NBUCK, 256, 0, stream>>>(partc, partr, cpos, rpos, srcoff, srcw, dis);

    // ---- layer 1 ----
    k_lin1<<<(N_NODES + 7) / 8, 256, 0, stream>>>(x, W1, b1, dis, hs1b);
    k_gather1<<<(N_NODES + 3) / 4, 256, 0, stream>>>(srcw, srcoff, dis, hs1b, hs2b);

    // ---- layer 2 (aggregate in 32-dim, lin2 fused into pool) ----
    k_gather2<<<(N_NODES + 3) / 4, 256, 0, stream>>>(srcw, srcoff, dis, hs2b, G, Sd);

    // ---- pooling + head ----
    k_lin2pool<<<(N_NODES + 255) / 256, 256, 0, stream>>>(G, Sd, W2, b2, batch, sums);
    k_final<<<1, 640, 0, stream>>>(sums, batch, Wf, bf, out);
}